// Round 13
// baseline (226.978 us; speedup 1.0000x reference)
//
#include <hip/hip_runtime.h>

#define DIM 64
#define EPS 1e-8f
#define ALPHA_T 0.1f
#define BSH 8                 // bucket = 256 rows
#define FINE_CAP 14336        // LDS staging capacity (57 KB); mean bucket = 4096

typedef _Float16 f16x8 __attribute__((ext_vector_type(8)));

static __device__ __forceinline__ unsigned short f32_to_f16bits(float f) {
    union { _Float16 h; unsigned short u; } cv; cv.h = (_Float16)f; return cv.u;
}
static __device__ __forceinline__ float f16bits_to_f32(unsigned short u) {
    union { _Float16 h; unsigned short u; } cv; cv.u = u; return (float)cv.h;
}

// ---- software OCP e4m3fn encode (|v| <= 1 in practice; handles subnormals) ----
static __device__ __forceinline__ unsigned char e4m3_encode(float v) {
    unsigned s = (__float_as_uint(v) >> 31) << 7;
    float a = fabsf(v);
    if (!(a >= 0.0009765625f)) return (unsigned char)s;   // < 2^-10 -> +/-0
    if (a >= 448.f) return (unsigned char)(s | 0x7E);
    int E; float f = frexpf(a, &E);    // a = f*2^E, f in [0.5,1)
    int eb = E + 6;                    // biased exponent (E-1+7)
    if (eb <= 0) {                     // subnormal grid: round(a*512); 8 rolls to 0x08=2^-6
        int q = (int)(a * 512.f + 0.5f);
        return (unsigned char)(s | q);
    }
    int q = (int)(f * 16.f + 0.5f) - 8;   // 0..8
    if (q == 8) { ++eb; q = 0; }
    if (eb > 15) return (unsigned char)(s | 0x7E);
    return (unsigned char)(s | (eb << 3) | q);
}

static __device__ __forceinline__ float e4m3_decode(int b) {
    int E = (b >> 3) & 0xF, m = b & 7;
    float v = E ? ldexpf(1.0f + m * 0.125f, E - 7) : ldexpf(m * 0.125f, -6);
    return (b & 0x80) ? -v : v;
}

// ---- norm + normalized f16 + fp8 tables: one wave per node ----
__global__ void norm_hat_kernel(const float* __restrict__ embs,
                                _Float16* __restrict__ hat,
                                unsigned char* __restrict__ hat8,
                                float* __restrict__ nrm, int n) {
    int node = (blockIdx.x * blockDim.x + threadIdx.x) >> 6;
    int lane = threadIdx.x & 63;
    if (node >= n) return;
    float v = embs[node * DIM + lane];
    float ss = v * v;
    #pragma unroll
    for (int m = 1; m < 64; m <<= 1) ss += __shfl_xor(ss, m);
    float nr = fmaxf(sqrtf(ss), EPS);
    float h = v / nr;
    hat[node * DIM + lane] = (_Float16)h;
    hat8[node * DIM + lane] = e4m3_encode(h);
    if (lane == 0) nrm[node] = nr;
}

// ---- per-bucket histogram (LDS-merged) ----
__global__ void bucket_hist_kernel(const int* __restrict__ t_idx, const int* __restrict__ s_idx,
                                   int* __restrict__ bhist, int E, int nbk) {
    __shared__ int h[256];
    const int* idx = blockIdx.y ? s_idx : t_idx;
    int tid = threadIdx.x;
    h[tid] = 0;
    __syncthreads();
    for (int e = blockIdx.x * blockDim.x + tid; e < E; e += gridDim.x * blockDim.x)
        atomicAdd(&h[idx[e] >> BSH], 1);
    __syncthreads();
    if (tid < nbk && h[tid]) atomicAdd(&bhist[blockIdx.y * nbk + tid], h[tid]);
}

// ---- exclusive scan of bucket counts -> bucket bases (1 wave per set) ----
__global__ void bucket_scan_kernel(const int* __restrict__ bhist, int* __restrict__ bo, int nbk) {
    const int* h = bhist + blockIdx.x * nbk;
    int* o = bo + blockIdx.x * nbk;
    int lane = threadIdx.x;
    int carry = 0;
    for (int base = 0; base < nbk; base += 64) {
        int i = base + lane;
        int x = (i < nbk) ? h[i] : 0;
        int inc = x;
        #pragma unroll
        for (int off = 1; off < 64; off <<= 1) {
            int y = __shfl_up(inc, off);
            if (lane >= off) inc += y;
        }
        if (i < nbk) o[i] = carry + inc - x;
        carry += __shfl(inc, 63);
    }
}

// ---- multisplit: bin tile of 4096 edges by bucket in LDS, write coalesced runs ----
__global__ void fill_ms_kernel(const int* __restrict__ t_idx, const float* __restrict__ t_val,
                               const int* __restrict__ s_idx, const float* __restrict__ s_val,
                               const int* __restrict__ bo, int* __restrict__ bcur,
                               int2* __restrict__ coarse, int E, int nbk) {
    __shared__ int hist[256];
    __shared__ int excl[256];
    __shared__ int cur[256];
    __shared__ int gbase[256];
    __shared__ int wsum[4];
    __shared__ int2 stage[4096];
    int set = blockIdx.y;
    const int* idx = set ? s_idx : t_idx;
    const float* val = set ? s_val : t_val;
    int tid = threadIdx.x;
    int lane = tid & 63, wid = tid >> 6;
    int tile0 = blockIdx.x * 4096;
    hist[tid] = 0; cur[tid] = 0;
    __syncthreads();
    int r_[16]; int m_[16]; float v_[16];
    #pragma unroll
    for (int i = 0; i < 16; ++i) {
        int j = tile0 + i * 256 + tid;
        if (j < E) {
            int r = idx[j];
            int c = idx[E + j];
            r_[i] = r;
            m_[i] = (c & 0xFFFF) | ((r & 255) << 16);  // c:16b | r_local:8b
            v_[i] = val[j];
            atomicAdd(&hist[r >> BSH], 1);
        } else r_[i] = -1;
    }
    __syncthreads();
    // wave-shfl exclusive scan over 256 elements (2 barriers)
    int x = hist[tid];
    int inc = x;
    #pragma unroll
    for (int off = 1; off < 64; off <<= 1) {
        int y = __shfl_up(inc, off);
        if (lane >= off) inc += y;
    }
    if (lane == 63) wsum[wid] = inc;
    __syncthreads();
    int woff = 0;
    #pragma unroll
    for (int w = 0; w < 4; ++w) if (w < wid) woff += wsum[w];
    int myexc = woff + inc - x;
    excl[tid] = myexc;
    if (tid < nbk && x > 0)
        gbase[tid] = bo[set * nbk + tid] + atomicAdd(&bcur[set * nbk + tid], x);
    __syncthreads();
    // stage bucket-grouped
    #pragma unroll
    for (int i = 0; i < 16; ++i) {
        if (r_[i] >= 0) {
            int b = r_[i] >> BSH;
            int p = excl[b] + atomicAdd(&cur[b], 1);
            stage[p] = make_int2(m_[i], __float_as_int(v_[i]));
        }
    }
    __syncthreads();
    // copy out per-bucket runs (wave-parallel, coalesced)
    int2* cset = coarse + (size_t)set * E;
    for (int b = wid; b < nbk; b += 4) {
        int cb = hist[b];
        if (!cb) continue;
        int sb = excl[b];
        int gb = gbase[b];
        for (int k = lane; k < cb; k += 64)
            cset[gb + k] = stage[sb + k];
    }
}

// ---- fine pass: per-bucket row grouping in LDS; emits rp_abs/cnt + packed pairs ----
__global__ void fill_fine_kernel(const int2* __restrict__ coarse,
                                 const int* __restrict__ bo, const int* __restrict__ bhist,
                                 unsigned int* __restrict__ pairs,
                                 int* __restrict__ rp_abs, int* __restrict__ cnt,
                                 int E, int n, int nbk) {
    __shared__ int h[256];
    __shared__ int exc[256];
    __shared__ int cur[256];
    __shared__ int wsum[4];
    __shared__ unsigned int outbuf[FINE_CAP];
    int set = blockIdx.y;
    int b = blockIdx.x;
    const int2* src = coarse + (size_t)set * E;
    unsigned int* dst = pairs + (size_t)set * E;
    int base = bo[set * nbk + b];
    int cb   = bhist[set * nbk + b];
    int tid = threadIdx.x;
    int lane = tid & 63, wid = tid >> 6;
    h[tid] = 0; cur[tid] = 0;
    __syncthreads();
    for (int k = tid; k < cb; k += 256)
        atomicAdd(&h[(src[base + k].x >> 16) & 255], 1);
    __syncthreads();
    // wave-shfl exclusive scan over 256 elements
    int x = h[tid];
    int inc = x;
    #pragma unroll
    for (int off = 1; off < 64; off <<= 1) {
        int y = __shfl_up(inc, off);
        if (lane >= off) inc += y;
    }
    if (lane == 63) wsum[wid] = inc;
    __syncthreads();
    int woff = 0;
    #pragma unroll
    for (int w = 0; w < 4; ++w) if (w < wid) woff += wsum[w];
    int myexc = woff + inc - x;
    exc[tid] = myexc;
    int r = (b << BSH) + tid;
    if (r < n) {
        rp_abs[set * n + r] = base + myexc;
        cnt[set * n + r] = x;
    }
    __syncthreads();
    bool ovf = cb > FINE_CAP;
    for (int k = tid; k < cb; k += 256) {
        int2 pr = src[base + k];
        int rl = (pr.x >> 16) & 255;
        unsigned int packed = (unsigned int)(pr.x & 0xFFFF)
                            | ((unsigned int)f32_to_f16bits(__int_as_float(pr.y)) << 16);
        int slot = exc[rl] + atomicAdd(&cur[rl], 1);
        if (!ovf) outbuf[slot] = packed;
        else      dst[base + slot] = packed;   // impossible-by-stats fallback
    }
    __syncthreads();
    if (!ovf)
        for (int k = tid; k < cb; k += 256)
            dst[base + k] = outbuf[k];
}

// ---- fused refine + SpMM: one wave per row, 16 edges in flight (4 lanes/edge) ----
// SECOND: dot c-side from fp8 LDS-LUT (L2-resident 3.2MB table); value from f16 msg.
template <bool SECOND>
__global__ void spmm_kernel(const _Float16* __restrict__ hat,
                            const _Float16* __restrict__ msg_h,
                            const unsigned char* __restrict__ hat8,
                            const float* __restrict__ nrm,
                            const int* __restrict__ rp_abs,
                            const int* __restrict__ cnt,
                            const unsigned int* __restrict__ pairs,
                            float* __restrict__ out_f32,
                            _Float16* __restrict__ out_f16,
                            int n_rows) {
    __shared__ float lut[256];
    if (SECOND) {
        lut[threadIdx.x] = e4m3_decode((int)threadIdx.x);
        __syncthreads();
    }
    int r = (blockIdx.x * blockDim.x + threadIdx.x) >> 6;
    int lane = threadIdx.x & 63;
    if (r >= n_rows) return;
    int g = lane >> 2;          // edge slot within wave (16 groups)
    int l = lane & 3;           // dim-16-chunk index

    const f16x8* qrow = (const f16x8*)&hat[(size_t)r * DIM + l * 16];
    f16x8 qh0 = qrow[0], qh1 = qrow[1];
    float qf[16];
    #pragma unroll
    for (int i = 0; i < 8; ++i) { qf[i] = (float)qh0[i]; qf[8 + i] = (float)qh1[i]; }

    int beg = rp_abs[r];
    int c_ = cnt[r];
    float acc[16];
    #pragma unroll
    for (int i = 0; i < 16; ++i) acc[i] = 0.0f;

    unsigned int p = (g < c_) ? pairs[beg + g] : 0u;
    for (int k0 = 0; k0 < c_; k0 += 16) {
        int nidx = k0 + 16 + g;
        unsigned int pn = (nidx < c_) ? pairs[beg + nidx] : 0u;

        int c = p & 0xFFFF;
        float w = f16bits_to_f32((unsigned short)(p >> 16));   // 0 for invalid lanes
        float dot = 0.0f;

        if (SECOND) {
            uint4 cb = *(const uint4*)&hat8[(size_t)c * DIM + l * 16];
            const f16x8* mrow = (const f16x8*)&msg_h[(size_t)c * DIM + l * 16];
            f16x8 mh0 = mrow[0], mh1 = mrow[1];
            unsigned int wws[4] = {cb.x, cb.y, cb.z, cb.w};
            #pragma unroll
            for (int wi = 0; wi < 4; ++wi) {
                #pragma unroll
                for (int j = 0; j < 4; ++j)
                    dot += qf[wi * 4 + j] * lut[(wws[wi] >> (8 * j)) & 0xFF];
            }
            dot += __shfl_xor(dot, 1);
            dot += __shfl_xor(dot, 2);
            float sn = fminf(fmaxf((dot + 1.0f) * 0.5f, 0.0f), 1.0f);
            float wr = w * (1.0f + ALPHA_T * sn);
            #pragma unroll
            for (int i = 0; i < 8; ++i) {
                acc[i]     += wr * (float)mh0[i];
                acc[8 + i] += wr * (float)mh1[i];
            }
        } else {
            const f16x8* crow = (const f16x8*)&hat[(size_t)c * DIM + l * 16];
            f16x8 ch0 = crow[0], ch1 = crow[1];
            #pragma unroll
            for (int i = 0; i < 8; ++i) {
                dot += qf[i] * (float)ch0[i];
                dot += qf[8 + i] * (float)ch1[i];
            }
            dot += __shfl_xor(dot, 1);
            dot += __shfl_xor(dot, 2);
            float sn = fminf(fmaxf((dot + 1.0f) * 0.5f, 0.0f), 1.0f);
            float wr = w * (1.0f + ALPHA_T * sn);
            float s = wr * nrm[c];
            #pragma unroll
            for (int i = 0; i < 8; ++i) {
                acc[i]     += s * (float)ch0[i];
                acc[8 + i] += s * (float)ch1[i];
            }
        }
        p = pn;
    }

    // cross-group reduce (masks 4,8,16,32)
    #pragma unroll
    for (int m = 4; m < 64; m <<= 1) {
        #pragma unroll
        for (int i = 0; i < 16; ++i) acc[i] += __shfl_xor(acc[i], m);
    }

    if (g == 0) {
        if (SECOND) {
            float4* o = (float4*)&out_f32[(size_t)r * DIM + l * 16];
            o[0] = make_float4(acc[0], acc[1], acc[2], acc[3]);
            o[1] = make_float4(acc[4], acc[5], acc[6], acc[7]);
            o[2] = make_float4(acc[8], acc[9], acc[10], acc[11]);
            o[3] = make_float4(acc[12], acc[13], acc[14], acc[15]);
        } else {
            f16x8 h0, h1;
            #pragma unroll
            for (int i = 0; i < 8; ++i) {
                h0[i] = (_Float16)acc[i];
                h1[i] = (_Float16)acc[8 + i];
            }
            f16x8* o = (f16x8*)&out_f16[(size_t)r * DIM + l * 16];
            o[0] = h0;
            o[1] = h1;
        }
    }
}

// ---- fallback: atomic scatter path ----
__global__ void norm_kernel_f(const float* __restrict__ embs,
                              float* __restrict__ inv_norm, int n_nodes) {
    int node = (blockIdx.x * blockDim.x + threadIdx.x) >> 6;
    int lane = threadIdx.x & 63;
    if (node >= n_nodes) return;
    float v = embs[node * DIM + lane];
    float ss = v * v;
    #pragma unroll
    for (int m = 1; m < 64; m <<= 1) ss += __shfl_xor(ss, m);
    if (lane == 0) inv_norm[node] = 1.0f / fmaxf(sqrtf(ss), EPS);
}

__global__ void refine_spmm_atomic(const float* __restrict__ embs,
                                   const float* __restrict__ x,
                                   const int* __restrict__ eidx,
                                   const float* __restrict__ eval_,
                                   const float* __restrict__ inv_norm,
                                   float* __restrict__ out, int n_edges) {
    int wave = (blockIdx.x * blockDim.x + threadIdx.x) >> 6;
    int lane = threadIdx.x & 63;
    if (wave >= n_edges) return;
    int r0 = eidx[wave];
    int r1 = eidx[n_edges + wave];
    float s = embs[r0 * DIM + lane];
    float t = embs[r1 * DIM + lane];
    float dot = s * t;
    #pragma unroll
    for (int m = 1; m < 64; m <<= 1) dot += __shfl_xor(dot, m);
    float sim = dot * inv_norm[r0] * inv_norm[r1];
    float sn = fminf(fmaxf((sim + 1.0f) * 0.5f, 0.0f), 1.0f);
    float refined = eval_[wave] * (1.0f + ALPHA_T * sn);
    float xv = (x == embs) ? t : x[r1 * DIM + lane];
    atomicAdd(&out[r0 * DIM + lane], refined * xv);
}

extern "C" void kernel_launch(void* const* d_in, const int* in_sizes, int n_in,
                              void* d_out, int out_size, void* d_ws, size_t ws_size,
                              hipStream_t stream) {
    const float* embs    = (const float*)d_in[0];
    const int*   src_idx = (const int*)d_in[1];
    const float* src_val = (const float*)d_in[2];
    const int*   tar_idx = (const int*)d_in[3];
    const float* tar_val = (const float*)d_in[4];
    float* out = (float*)d_out;

    int n = in_sizes[0] / DIM;       // 50000
    int E = in_sizes[2];             // 800000
    int nbk = (n + 255) >> BSH;      // 196 buckets per set

    // workspace layout (words)
    int* w = (int*)d_ws;
    size_t wo = 0;
    int* bhist = w + wo; wo += 2 * (size_t)nbk;
    int* bcur  = w + wo; wo += 2 * (size_t)nbk;
    int* bo    = w + wo; wo += 2 * (size_t)nbk;
    int* rp    = w + wo; wo += 2 * (size_t)n;   // per set: rp_abs
    int* cnt   = w + wo; wo += 2 * (size_t)n;   // per set: row counts
    float* nrm = (float*)(w + wo); wo += (size_t)n;
    wo = (wo + 3) & ~(size_t)3;
    unsigned int* pairs = (unsigned int*)(w + wo); wo += 2 * (size_t)E;
    wo = (wo + 3) & ~(size_t)3;
    unsigned char* hat8 = (unsigned char*)(w + wo); wo += 16 * (size_t)n;  // fp8 table (3.2MB)
    wo = (wo + 3) & ~(size_t)3;
    // region: coarse pairs (dead after fill_fine) aliases hat+msg
    size_t region_words = (size_t)4 * E > (size_t)64 * n ? (size_t)4 * E : (size_t)64 * n;
    int2* coarse    = (int2*)(w + wo);
    _Float16* hat   = (_Float16*)(w + wo);
    _Float16* msg_h = hat + (size_t)n * DIM;
    wo += region_words;
    size_t needed = wo * 4;

    int nodeBlocks = (n * 64 + 255) / 256;
    int tiles = (E + 4095) / 4096;

    if (ws_size >= needed && n <= 65536 && nbk <= 256) {
        hipMemsetAsync(bhist, 0, 4 * (size_t)nbk * sizeof(int), stream);  // bhist + bcur
        bucket_hist_kernel<<<dim3(256, 2), 256, 0, stream>>>(tar_idx, src_idx, bhist, E, nbk);
        bucket_scan_kernel<<<2, 64, 0, stream>>>(bhist, bo, nbk);
        fill_ms_kernel<<<dim3(tiles, 2), 256, 0, stream>>>(
            tar_idx, tar_val, src_idx, src_val, bo, bcur, coarse, E, nbk);
        fill_fine_kernel<<<dim3(nbk, 2), 256, 0, stream>>>(
            coarse, bo, bhist, pairs, rp, cnt, E, n, nbk);
        // coarse dead; hat/msg alias it from here on
        norm_hat_kernel<<<nodeBlocks, 256, 0, stream>>>(embs, hat, hat8, nrm, n);
        // SpMM 1 (tar, set 0): msg = A_tar(refined) @ embs  (f16 out)
        spmm_kernel<false><<<nodeBlocks, 256, 0, stream>>>(
            hat, nullptr, hat8, nrm, rp, cnt, pairs, nullptr, msg_h, n);
        // SpMM 2 (src, set 1): out = A_src(refined) @ msg   (f32 out)
        spmm_kernel<true><<<nodeBlocks, 256, 0, stream>>>(
            hat, msg_h, hat8, nrm, rp + n, cnt + n, pairs + (size_t)E, out, nullptr, n);
    } else {
        // fallback: atomic path (needs (n + n*DIM)*4 bytes)
        float* inv_norm = (float*)d_ws;
        float* msg_tar  = inv_norm + n;
        hipMemsetAsync(msg_tar, 0, (size_t)n * DIM * sizeof(float), stream);
        hipMemsetAsync(d_out, 0, (size_t)out_size * sizeof(float), stream);
        norm_kernel_f<<<nodeBlocks, 256, 0, stream>>>(embs, inv_norm, n);
        refine_spmm_atomic<<<(E * 64 + 255) / 256, 256, 0, stream>>>(
            embs, embs, tar_idx, tar_val, inv_norm, msg_tar, E);
        refine_spmm_atomic<<<(E * 64 + 255) / 256, 256, 0, stream>>>(
            embs, msg_tar, src_idx, src_val, inv_norm, out, E);
    }
}

// Round 14
// 216.674 us; speedup vs baseline: 1.0476x; 1.0476x over previous
//
#include <hip/hip_runtime.h>

#define DIM 64
#define EPS 1e-8f
#define ALPHA_T 0.1f
#define BSH 8                 // bucket = 256 rows
#define FINE_CAP 14336        // LDS staging capacity (57 KB); mean bucket = 4096

typedef _Float16 f16x8 __attribute__((ext_vector_type(8)));
typedef float f32x2 __attribute__((ext_vector_type(2)));

static __device__ __forceinline__ unsigned short f32_to_f16bits(float f) {
    union { _Float16 h; unsigned short u; } cv; cv.h = (_Float16)f; return cv.u;
}
static __device__ __forceinline__ float f16bits_to_f32(unsigned short u) {
    union { _Float16 h; unsigned short u; } cv; cv.u = u; return (float)cv.h;
}

// ---- software OCP e4m3fn encode (|v| <= 1 in practice; handles subnormals) ----
static __device__ __forceinline__ unsigned char e4m3_encode(float v) {
    unsigned s = (__float_as_uint(v) >> 31) << 7;
    float a = fabsf(v);
    if (!(a >= 0.0009765625f)) return (unsigned char)s;   // < 2^-10 -> +/-0
    if (a >= 448.f) return (unsigned char)(s | 0x7E);
    int E; float f = frexpf(a, &E);    // a = f*2^E, f in [0.5,1)
    int eb = E + 6;                    // biased exponent (E-1+7)
    if (eb <= 0) {                     // subnormal grid: round(a*512)
        int q = (int)(a * 512.f + 0.5f);
        return (unsigned char)(s | q);
    }
    int q = (int)(f * 16.f + 0.5f) - 8;   // 0..8
    if (q == 8) { ++eb; q = 0; }
    if (eb > 15) return (unsigned char)(s | 0x7E);
    return (unsigned char)(s | (eb << 3) | q);
}

// ---- register-only fp8x4 -> f32x4 decode: HW cvt on gfx950, ldexp fallback ----
static __device__ __forceinline__ void fp8x4_to_f32(unsigned int w4, float* o) {
#if __has_builtin(__builtin_amdgcn_cvt_pk_f32_fp8)
    f32x2 lo = __builtin_amdgcn_cvt_pk_f32_fp8((int)w4, false);
    f32x2 hi = __builtin_amdgcn_cvt_pk_f32_fp8((int)w4, true);
    o[0] = lo[0]; o[1] = lo[1]; o[2] = hi[0]; o[3] = hi[1];
#else
    #pragma unroll
    for (int j = 0; j < 4; ++j) {
        unsigned b = (w4 >> (8 * j)) & 0xFF;
        unsigned x = b & 0x7F, E = x >> 3, m = x & 7;
        float v = ldexpf((float)(E ? 8 + m : m), E ? (int)E - 10 : -9);
        o[j] = (b & 0x80) ? -v : v;
    }
#endif
}

// ---- norm + normalized f16 + fp8 tables: one wave per node ----
__global__ void norm_hat_kernel(const float* __restrict__ embs,
                                _Float16* __restrict__ hat,
                                unsigned char* __restrict__ hat8,
                                float* __restrict__ nrm, int n) {
    int node = (blockIdx.x * blockDim.x + threadIdx.x) >> 6;
    int lane = threadIdx.x & 63;
    if (node >= n) return;
    float v = embs[node * DIM + lane];
    float ss = v * v;
    #pragma unroll
    for (int m = 1; m < 64; m <<= 1) ss += __shfl_xor(ss, m);
    float nr = fmaxf(sqrtf(ss), EPS);
    float h = v / nr;
    hat[node * DIM + lane] = (_Float16)h;
    hat8[node * DIM + lane] = e4m3_encode(h);
    if (lane == 0) nrm[node] = nr;
}

// ---- per-bucket histogram (LDS-merged) ----
__global__ void bucket_hist_kernel(const int* __restrict__ t_idx, const int* __restrict__ s_idx,
                                   int* __restrict__ bhist, int E, int nbk) {
    __shared__ int h[256];
    const int* idx = blockIdx.y ? s_idx : t_idx;
    int tid = threadIdx.x;
    h[tid] = 0;
    __syncthreads();
    for (int e = blockIdx.x * blockDim.x + tid; e < E; e += gridDim.x * blockDim.x)
        atomicAdd(&h[idx[e] >> BSH], 1);
    __syncthreads();
    if (tid < nbk && h[tid]) atomicAdd(&bhist[blockIdx.y * nbk + tid], h[tid]);
}

// ---- exclusive scan of bucket counts -> bucket bases (1 wave per set) ----
__global__ void bucket_scan_kernel(const int* __restrict__ bhist, int* __restrict__ bo, int nbk) {
    const int* h = bhist + blockIdx.x * nbk;
    int* o = bo + blockIdx.x * nbk;
    int lane = threadIdx.x;
    int carry = 0;
    for (int base = 0; base < nbk; base += 64) {
        int i = base + lane;
        int x = (i < nbk) ? h[i] : 0;
        int inc = x;
        #pragma unroll
        for (int off = 1; off < 64; off <<= 1) {
            int y = __shfl_up(inc, off);
            if (lane >= off) inc += y;
        }
        if (i < nbk) o[i] = carry + inc - x;
        carry += __shfl(inc, 63);
    }
}

// ---- multisplit: bin tile of 4096 edges by bucket in LDS, write coalesced runs ----
__global__ void fill_ms_kernel(const int* __restrict__ t_idx, const float* __restrict__ t_val,
                               const int* __restrict__ s_idx, const float* __restrict__ s_val,
                               const int* __restrict__ bo, int* __restrict__ bcur,
                               int2* __restrict__ coarse, int E, int nbk) {
    __shared__ int hist[256];
    __shared__ int excl[256];
    __shared__ int cur[256];
    __shared__ int gbase[256];
    __shared__ int wsum[4];
    __shared__ int2 stage[4096];
    int set = blockIdx.y;
    const int* idx = set ? s_idx : t_idx;
    const float* val = set ? s_val : t_val;
    int tid = threadIdx.x;
    int lane = tid & 63, wid = tid >> 6;
    int tile0 = blockIdx.x * 4096;
    hist[tid] = 0; cur[tid] = 0;
    __syncthreads();
    int r_[16]; int m_[16]; float v_[16];
    #pragma unroll
    for (int i = 0; i < 16; ++i) {
        int j = tile0 + i * 256 + tid;
        if (j < E) {
            int r = idx[j];
            int c = idx[E + j];
            r_[i] = r;
            m_[i] = (c & 0xFFFF) | ((r & 255) << 16);  // c:16b | r_local:8b
            v_[i] = val[j];
            atomicAdd(&hist[r >> BSH], 1);
        } else r_[i] = -1;
    }
    __syncthreads();
    // wave-shfl exclusive scan over 256 elements (2 barriers)
    int x = hist[tid];
    int inc = x;
    #pragma unroll
    for (int off = 1; off < 64; off <<= 1) {
        int y = __shfl_up(inc, off);
        if (lane >= off) inc += y;
    }
    if (lane == 63) wsum[wid] = inc;
    __syncthreads();
    int woff = 0;
    #pragma unroll
    for (int w = 0; w < 4; ++w) if (w < wid) woff += wsum[w];
    int myexc = woff + inc - x;
    excl[tid] = myexc;
    if (tid < nbk && x > 0)
        gbase[tid] = bo[set * nbk + tid] + atomicAdd(&bcur[set * nbk + tid], x);
    __syncthreads();
    // stage bucket-grouped
    #pragma unroll
    for (int i = 0; i < 16; ++i) {
        if (r_[i] >= 0) {
            int b = r_[i] >> BSH;
            int p = excl[b] + atomicAdd(&cur[b], 1);
            stage[p] = make_int2(m_[i], __float_as_int(v_[i]));
        }
    }
    __syncthreads();
    // copy out per-bucket runs (wave-parallel, coalesced)
    int2* cset = coarse + (size_t)set * E;
    for (int b = wid; b < nbk; b += 4) {
        int cb = hist[b];
        if (!cb) continue;
        int sb = excl[b];
        int gb = gbase[b];
        for (int k = lane; k < cb; k += 64)
            cset[gb + k] = stage[sb + k];
    }
}

// ---- fine pass: per-bucket row grouping in LDS; emits rp_abs/cnt + packed pairs ----
__global__ void fill_fine_kernel(const int2* __restrict__ coarse,
                                 const int* __restrict__ bo, const int* __restrict__ bhist,
                                 unsigned int* __restrict__ pairs,
                                 int* __restrict__ rp_abs, int* __restrict__ cnt,
                                 int E, int n, int nbk) {
    __shared__ int h[256];
    __shared__ int exc[256];
    __shared__ int cur[256];
    __shared__ int wsum[4];
    __shared__ unsigned int outbuf[FINE_CAP];
    int set = blockIdx.y;
    int b = blockIdx.x;
    const int2* src = coarse + (size_t)set * E;
    unsigned int* dst = pairs + (size_t)set * E;
    int base = bo[set * nbk + b];
    int cb   = bhist[set * nbk + b];
    int tid = threadIdx.x;
    int lane = tid & 63, wid = tid >> 6;
    h[tid] = 0; cur[tid] = 0;
    __syncthreads();
    for (int k = tid; k < cb; k += 256)
        atomicAdd(&h[(src[base + k].x >> 16) & 255], 1);
    __syncthreads();
    // wave-shfl exclusive scan over 256 elements
    int x = h[tid];
    int inc = x;
    #pragma unroll
    for (int off = 1; off < 64; off <<= 1) {
        int y = __shfl_up(inc, off);
        if (lane >= off) inc += y;
    }
    if (lane == 63) wsum[wid] = inc;
    __syncthreads();
    int woff = 0;
    #pragma unroll
    for (int w = 0; w < 4; ++w) if (w < wid) woff += wsum[w];
    int myexc = woff + inc - x;
    exc[tid] = myexc;
    int r = (b << BSH) + tid;
    if (r < n) {
        rp_abs[set * n + r] = base + myexc;
        cnt[set * n + r] = x;
    }
    __syncthreads();
    bool ovf = cb > FINE_CAP;
    for (int k = tid; k < cb; k += 256) {
        int2 pr = src[base + k];
        int rl = (pr.x >> 16) & 255;
        unsigned int packed = (unsigned int)(pr.x & 0xFFFF)
                            | ((unsigned int)f32_to_f16bits(__int_as_float(pr.y)) << 16);
        int slot = exc[rl] + atomicAdd(&cur[rl], 1);
        if (!ovf) outbuf[slot] = packed;
        else      dst[base + slot] = packed;   // impossible-by-stats fallback
    }
    __syncthreads();
    if (!ovf)
        for (int k = tid; k < cb; k += 256)
            dst[base + k] = outbuf[k];
}

// ---- fused refine + SpMM: one wave per row, 16 edges in flight (4 lanes/edge) ----
// SECOND: dot c-side from fp8 (register HW-cvt decode, 3.2MB L2-resident table).
template <bool SECOND>
__global__ void spmm_kernel(const _Float16* __restrict__ hat,
                            const _Float16* __restrict__ msg_h,
                            const unsigned char* __restrict__ hat8,
                            const float* __restrict__ nrm,
                            const int* __restrict__ rp_abs,
                            const int* __restrict__ cnt,
                            const unsigned int* __restrict__ pairs,
                            float* __restrict__ out_f32,
                            _Float16* __restrict__ out_f16,
                            int n_rows) {
    int r = (blockIdx.x * blockDim.x + threadIdx.x) >> 6;
    int lane = threadIdx.x & 63;
    if (r >= n_rows) return;
    int g = lane >> 2;          // edge slot within wave (16 groups)
    int l = lane & 3;           // dim-16-chunk index

    const f16x8* qrow = (const f16x8*)&hat[(size_t)r * DIM + l * 16];
    f16x8 qh0 = qrow[0], qh1 = qrow[1];
    float qf[16];
    #pragma unroll
    for (int i = 0; i < 8; ++i) { qf[i] = (float)qh0[i]; qf[8 + i] = (float)qh1[i]; }

    int beg = rp_abs[r];
    int c_ = cnt[r];
    float acc[16];
    #pragma unroll
    for (int i = 0; i < 16; ++i) acc[i] = 0.0f;

    unsigned int p = (g < c_) ? pairs[beg + g] : 0u;
    for (int k0 = 0; k0 < c_; k0 += 16) {
        int nidx = k0 + 16 + g;
        unsigned int pn = (nidx < c_) ? pairs[beg + nidx] : 0u;

        int c = p & 0xFFFF;
        float w = f16bits_to_f32((unsigned short)(p >> 16));   // 0 for invalid lanes
        float dot = 0.0f;

        if (SECOND) {
            uint4 cb = *(const uint4*)&hat8[(size_t)c * DIM + l * 16];
            const f16x8* mrow = (const f16x8*)&msg_h[(size_t)c * DIM + l * 16];
            f16x8 mh0 = mrow[0], mh1 = mrow[1];
            float cf[16];
            fp8x4_to_f32(cb.x, cf + 0);
            fp8x4_to_f32(cb.y, cf + 4);
            fp8x4_to_f32(cb.z, cf + 8);
            fp8x4_to_f32(cb.w, cf + 12);
            #pragma unroll
            for (int i = 0; i < 16; ++i) dot += qf[i] * cf[i];
            dot += __shfl_xor(dot, 1);
            dot += __shfl_xor(dot, 2);
            float sn = fminf(fmaxf((dot + 1.0f) * 0.5f, 0.0f), 1.0f);
            float wr = w * (1.0f + ALPHA_T * sn);
            #pragma unroll
            for (int i = 0; i < 8; ++i) {
                acc[i]     += wr * (float)mh0[i];
                acc[8 + i] += wr * (float)mh1[i];
            }
        } else {
            const f16x8* crow = (const f16x8*)&hat[(size_t)c * DIM + l * 16];
            f16x8 ch0 = crow[0], ch1 = crow[1];
            #pragma unroll
            for (int i = 0; i < 8; ++i) {
                dot += qf[i] * (float)ch0[i];
                dot += qf[8 + i] * (float)ch1[i];
            }
            dot += __shfl_xor(dot, 1);
            dot += __shfl_xor(dot, 2);
            float sn = fminf(fmaxf((dot + 1.0f) * 0.5f, 0.0f), 1.0f);
            float wr = w * (1.0f + ALPHA_T * sn);
            float s = wr * nrm[c];
            #pragma unroll
            for (int i = 0; i < 8; ++i) {
                acc[i]     += s * (float)ch0[i];
                acc[8 + i] += s * (float)ch1[i];
            }
        }
        p = pn;
    }

    // cross-group reduce (masks 4,8,16,32)
    #pragma unroll
    for (int m = 4; m < 64; m <<= 1) {
        #pragma unroll
        for (int i = 0; i < 16; ++i) acc[i] += __shfl_xor(acc[i], m);
    }

    if (g == 0) {
        if (SECOND) {
            float4* o = (float4*)&out_f32[(size_t)r * DIM + l * 16];
            o[0] = make_float4(acc[0], acc[1], acc[2], acc[3]);
            o[1] = make_float4(acc[4], acc[5], acc[6], acc[7]);
            o[2] = make_float4(acc[8], acc[9], acc[10], acc[11]);
            o[3] = make_float4(acc[12], acc[13], acc[14], acc[15]);
        } else {
            f16x8 h0, h1;
            #pragma unroll
            for (int i = 0; i < 8; ++i) {
                h0[i] = (_Float16)acc[i];
                h1[i] = (_Float16)acc[8 + i];
            }
            f16x8* o = (f16x8*)&out_f16[(size_t)r * DIM + l * 16];
            o[0] = h0;
            o[1] = h1;
        }
    }
}

// ---- fallback: atomic scatter path ----
__global__ void norm_kernel_f(const float* __restrict__ embs,
                              float* __restrict__ inv_norm, int n_nodes) {
    int node = (blockIdx.x * blockDim.x + threadIdx.x) >> 6;
    int lane = threadIdx.x & 63;
    if (node >= n_nodes) return;
    float v = embs[node * DIM + lane];
    float ss = v * v;
    #pragma unroll
    for (int m = 1; m < 64; m <<= 1) ss += __shfl_xor(ss, m);
    if (lane == 0) inv_norm[node] = 1.0f / fmaxf(sqrtf(ss), EPS);
}

__global__ void refine_spmm_atomic(const float* __restrict__ embs,
                                   const float* __restrict__ x,
                                   const int* __restrict__ eidx,
                                   const float* __restrict__ eval_,
                                   const float* __restrict__ inv_norm,
                                   float* __restrict__ out, int n_edges) {
    int wave = (blockIdx.x * blockDim.x + threadIdx.x) >> 6;
    int lane = threadIdx.x & 63;
    if (wave >= n_edges) return;
    int r0 = eidx[wave];
    int r1 = eidx[n_edges + wave];
    float s = embs[r0 * DIM + lane];
    float t = embs[r1 * DIM + lane];
    float dot = s * t;
    #pragma unroll
    for (int m = 1; m < 64; m <<= 1) dot += __shfl_xor(dot, m);
    float sim = dot * inv_norm[r0] * inv_norm[r1];
    float sn = fminf(fmaxf((sim + 1.0f) * 0.5f, 0.0f), 1.0f);
    float refined = eval_[wave] * (1.0f + ALPHA_T * sn);
    float xv = (x == embs) ? t : x[r1 * DIM + lane];
    atomicAdd(&out[r0 * DIM + lane], refined * xv);
}

extern "C" void kernel_launch(void* const* d_in, const int* in_sizes, int n_in,
                              void* d_out, int out_size, void* d_ws, size_t ws_size,
                              hipStream_t stream) {
    const float* embs    = (const float*)d_in[0];
    const int*   src_idx = (const int*)d_in[1];
    const float* src_val = (const float*)d_in[2];
    const int*   tar_idx = (const int*)d_in[3];
    const float* tar_val = (const float*)d_in[4];
    float* out = (float*)d_out;

    int n = in_sizes[0] / DIM;       // 50000
    int E = in_sizes[2];             // 800000
    int nbk = (n + 255) >> BSH;      // 196 buckets per set

    // workspace layout (words)
    int* w = (int*)d_ws;
    size_t wo = 0;
    int* bhist = w + wo; wo += 2 * (size_t)nbk;
    int* bcur  = w + wo; wo += 2 * (size_t)nbk;
    int* bo    = w + wo; wo += 2 * (size_t)nbk;
    int* rp    = w + wo; wo += 2 * (size_t)n;   // per set: rp_abs
    int* cnt   = w + wo; wo += 2 * (size_t)n;   // per set: row counts
    float* nrm = (float*)(w + wo); wo += (size_t)n;
    wo = (wo + 3) & ~(size_t)3;
    unsigned int* pairs = (unsigned int*)(w + wo); wo += 2 * (size_t)E;
    wo = (wo + 3) & ~(size_t)3;
    unsigned char* hat8 = (unsigned char*)(w + wo); wo += 16 * (size_t)n;  // fp8 table (3.2MB)
    wo = (wo + 3) & ~(size_t)3;
    // region: coarse pairs (dead after fill_fine) aliases hat+msg
    size_t region_words = (size_t)4 * E > (size_t)64 * n ? (size_t)4 * E : (size_t)64 * n;
    int2* coarse    = (int2*)(w + wo);
    _Float16* hat   = (_Float16*)(w + wo);
    _Float16* msg_h = hat + (size_t)n * DIM;
    wo += region_words;
    size_t needed = wo * 4;

    int nodeBlocks = (n * 64 + 255) / 256;
    int tiles = (E + 4095) / 4096;

    if (ws_size >= needed && n <= 65536 && nbk <= 256) {
        hipMemsetAsync(bhist, 0, 4 * (size_t)nbk * sizeof(int), stream);  // bhist + bcur
        bucket_hist_kernel<<<dim3(256, 2), 256, 0, stream>>>(tar_idx, src_idx, bhist, E, nbk);
        bucket_scan_kernel<<<2, 64, 0, stream>>>(bhist, bo, nbk);
        fill_ms_kernel<<<dim3(tiles, 2), 256, 0, stream>>>(
            tar_idx, tar_val, src_idx, src_val, bo, bcur, coarse, E, nbk);
        fill_fine_kernel<<<dim3(nbk, 2), 256, 0, stream>>>(
            coarse, bo, bhist, pairs, rp, cnt, E, n, nbk);
        // coarse dead; hat/msg alias it from here on
        norm_hat_kernel<<<nodeBlocks, 256, 0, stream>>>(embs, hat, hat8, nrm, n);
        // SpMM 1 (tar, set 0): msg = A_tar(refined) @ embs  (f16 out)
        spmm_kernel<false><<<nodeBlocks, 256, 0, stream>>>(
            hat, nullptr, hat8, nrm, rp, cnt, pairs, nullptr, msg_h, n);
        // SpMM 2 (src, set 1): out = A_src(refined) @ msg   (f32 out)
        spmm_kernel<true><<<nodeBlocks, 256, 0, stream>>>(
            hat, msg_h, hat8, nrm, rp + n, cnt + n, pairs + (size_t)E, out, nullptr, n);
    } else {
        // fallback: atomic path (needs (n + n*DIM)*4 bytes)
        float* inv_norm = (float*)d_ws;
        float* msg_tar  = inv_norm + n;
        hipMemsetAsync(msg_tar, 0, (size_t)n * DIM * sizeof(float), stream);
        hipMemsetAsync(d_out, 0, (size_t)out_size * sizeof(float), stream);
        norm_kernel_f<<<nodeBlocks, 256, 0, stream>>>(embs, inv_norm, n);
        refine_spmm_atomic<<<(E * 64 + 255) / 256, 256, 0, stream>>>(
            embs, embs, tar_idx, tar_val, inv_norm, msg_tar, E);
        refine_spmm_atomic<<<(E * 64 + 255) / 256, 256, 0, stream>>>(
            embs, msg_tar, src_idx, src_val, inv_norm, out, E);
    }
}